// Round 1
// baseline (1035.460 us; speedup 1.0000x reference)
//
#include <hip/hip_runtime.h>
#include <math.h>

// ExpressionPerformer: B=16,G=2048,D=256,H=8,dh=32,FFN=1024,L=4
// h fp32 residual stream; GEMMs in bf16 MFMA (16x16x32), fp32 accum.
// Attention = chunked causal linear attention (C=64, NC=32):
//   A1: per-(b,h,chunk) S_c = K^T V (MFMA) + z_c = sum k
//   A2: exclusive prefix over chunks
//   B : P = K Q^T (masked), out = (P V + Q S_pref)/(q.z + rowsum P), h +=
// GEMM: 128x128 tile, BK=32, 4 waves, chunk-major LDS (conflict-free b128 reads).
// Round-1: plain ds_write staging (no global_load_lds builtin yet - compile safety).

#define GG 2048
#define DD 256
#define HD 32
#define NROWS 32768
#define NC 32
#define CS 64

typedef __attribute__((ext_vector_type(8))) short bf16x8;
typedef __attribute__((ext_vector_type(4))) float f32x4;

__device__ __forceinline__ short f2bf(float f) {
  union { float f; unsigned u; } v; v.f = f;
  unsigned r = v.u + 0x7FFFu + ((v.u >> 16) & 1u);
  return (short)(r >> 16);
}
__device__ __forceinline__ float bf2f(short s) {
  union { unsigned u; float f; } v; v.u = ((unsigned)(unsigned short)s) << 16;
  return v.f;
}

// ---------------- embed: h = gene_emb + [sin(x*invf), cos(x*invf)] (masked) ----
__global__ __launch_bounds__(64) void embed_kernel(
    const float* __restrict__ x, const float* __restrict__ ge,
    const float* __restrict__ invf, float* __restrict__ h) {
  int bg = blockIdx.x;
  int g = bg & (GG - 1);
  int lane = threadIdx.x;
  float xv = x[bg];
  int d = lane * 4;
  float4 e;
  if (lane < 32) {
    float4 f = *(const float4*)&invf[d];
    e.x = sinf(xv * f.x); e.y = sinf(xv * f.y);
    e.z = sinf(xv * f.z); e.w = sinf(xv * f.w);
  } else {
    float4 f = *(const float4*)&invf[d - 128];
    e.x = cosf(xv * f.x); e.y = cosf(xv * f.y);
    e.z = cosf(xv * f.z); e.w = cosf(xv * f.w);
  }
  if (xv == -10.0f) { e.x = 0.f; e.y = 0.f; e.z = 0.f; e.w = 0.f; }
  float4 gv = *(const float4*)&ge[(size_t)g * DD + d];
  float4 o; o.x = gv.x + e.x; o.y = gv.y + e.y; o.z = gv.z + e.z; o.w = gv.w + e.w;
  *(float4*)&h[(size_t)bg * DD + d] = o;
}

// ---------------- layernorm (row of 256) -> bf16 ------------------------------
__global__ __launch_bounds__(64) void ln_kernel(
    const float* __restrict__ h, const float* __restrict__ gamma,
    const float* __restrict__ beta, short* __restrict__ out) {
  int row = blockIdx.x, lane = threadIdx.x;
  float4 xv = *(const float4*)&h[(size_t)row * DD + lane * 4];
  float s = xv.x + xv.y + xv.z + xv.w;
#pragma unroll
  for (int o = 1; o < 64; o <<= 1) s += __shfl_xor(s, o);
  float mean = s * (1.0f / 256.0f);
  float a = xv.x - mean, b = xv.y - mean, c = xv.z - mean, d = xv.w - mean;
  float s2 = a * a + b * b + c * c + d * d;
#pragma unroll
  for (int o = 1; o < 64; o <<= 1) s2 += __shfl_xor(s2, o);
  float rstd = rsqrtf(s2 * (1.0f / 256.0f) + 1e-5f);
  float4 g = *(const float4*)&gamma[lane * 4];
  float4 bb = *(const float4*)&beta[lane * 4];
  short4 o4;
  o4.x = f2bf(a * rstd * g.x + bb.x);
  o4.y = f2bf(b * rstd * g.y + bb.y);
  o4.z = f2bf(c * rstd * g.z + bb.z);
  o4.w = f2bf(d * rstd * g.w + bb.w);
  *(short4*)&out[(size_t)row * DD + lane * 4] = o4;
}

// ---------------- weight convert+transpose: W[K][N] -> WT[N][K] bf16 ----------
__global__ __launch_bounds__(256) void prep_weights(
    const float* __restrict__ Wq, const float* __restrict__ Wk,
    const float* __restrict__ Wv, const float* __restrict__ WU,
    const float* __restrict__ WV,
    short* __restrict__ TQ, short* __restrict__ TK, short* __restrict__ TV,
    short* __restrict__ TU, short* __restrict__ TVd) {
  int zz = blockIdx.z, l = blockIdx.y;
  const float* src; short* dst; int Kd, Nd;
  if (zz == 0) { src = Wq; dst = TQ; Kd = 256; Nd = 256; }
  else if (zz == 1) { src = Wk; dst = TK; Kd = 256; Nd = 256; }
  else if (zz == 2) { src = Wv; dst = TV; Kd = 256; Nd = 256; }
  else if (zz == 3) { src = WU; dst = TU; Kd = 256; Nd = 1024; }
  else { src = WV; dst = TVd; Kd = 1024; Nd = 256; }
  int tot = Kd * Nd;
  int e = blockIdx.x * 256 + threadIdx.x;
  if (e >= tot) return;
  int n = e / Kd, k = e - n * Kd;
  dst[(size_t)l * tot + e] = f2bf(src[(size_t)l * tot + (size_t)k * Nd + n]);
}

// ---------------- bf16 MFMA GEMM: C = A[M,K] * BT[N,K]^T + bias ---------------
// epi 0: z<2 -> square, bf16 out (QKV);  1: gelu, bf16 out;  2: h += acc+bias
__global__ __launch_bounds__(256) void gemm_bf16(
    const short* __restrict__ A, const short* __restrict__ B0,
    const short* __restrict__ B1, const short* __restrict__ B2,
    const float* __restrict__ bias0, const float* __restrict__ bias1,
    const float* __restrict__ bias2,
    short* __restrict__ o0, short* __restrict__ o1, short* __restrict__ o2,
    float* __restrict__ outf, int N, int K, int epi) {
  __shared__ short As[4096];  // 128x32 bf16, 16B-chunk-major [kb][m]
  __shared__ short Bs[4096];  // 128x32 bf16 (rows of BT), chunk-major [kb][n]
  int z = blockIdx.z;
  const short* Bt = (z == 0) ? B0 : (z == 1) ? B1 : B2;
  const float* bias = (z == 0) ? bias0 : (z == 1) ? bias1 : bias2;
  short* outz = (z == 0) ? o0 : (z == 1) ? o1 : o2;
  int m0 = blockIdx.x * 128, n0 = blockIdx.y * 128;
  int tid = threadIdx.x;
  int lane = tid & 63, w = tid >> 6;
  int q = lane >> 4, r = lane & 15;
  int wm = (w >> 1) * 64, wn = (w & 1) * 64;
  f32x4 vzero = {0.f, 0.f, 0.f, 0.f};
  f32x4 acc[4][4];
#pragma unroll
  for (int i = 0; i < 4; ++i)
#pragma unroll
    for (int j = 0; j < 4; ++j) acc[i][j] = vzero;

  for (int k0 = 0; k0 < K; k0 += 32) {
    __syncthreads();
    {
      int c0 = tid, c1 = tid + 256;
      *(int4*)&As[c0 * 8] = *(const int4*)&A[(size_t)(m0 + (c0 & 127)) * K + k0 + (c0 >> 7) * 8];
      *(int4*)&As[c1 * 8] = *(const int4*)&A[(size_t)(m0 + (c1 & 127)) * K + k0 + (c1 >> 7) * 8];
      *(int4*)&Bs[c0 * 8] = *(const int4*)&Bt[(size_t)(n0 + (c0 & 127)) * K + k0 + (c0 >> 7) * 8];
      *(int4*)&Bs[c1 * 8] = *(const int4*)&Bt[(size_t)(n0 + (c1 & 127)) * K + k0 + (c1 >> 7) * 8];
    }
    __syncthreads();
    bf16x8 af[4], bfr[4];
#pragma unroll
    for (int mt = 0; mt < 4; ++mt)
      af[mt] = *(const bf16x8*)&As[(q * 128 + wm + mt * 16 + r) * 8];
#pragma unroll
    for (int nt = 0; nt < 4; ++nt)
      bfr[nt] = *(const bf16x8*)&Bs[(q * 128 + wn + nt * 16 + r) * 8];
#pragma unroll
    for (int mt = 0; mt < 4; ++mt)
#pragma unroll
      for (int nt = 0; nt < 4; ++nt)
        acc[mt][nt] = __builtin_amdgcn_mfma_f32_16x16x32_bf16(af[mt], bfr[nt], acc[mt][nt], 0, 0, 0);
  }

#pragma unroll
  for (int nt = 0; nt < 4; ++nt) {
    int n = n0 + wn + nt * 16 + r;
    float bvv = bias[n];
#pragma unroll
    for (int mt = 0; mt < 4; ++mt) {
#pragma unroll
      for (int rr = 0; rr < 4; ++rr) {
        int m = m0 + wm + mt * 16 + q * 4 + rr;
        float v = acc[mt][nt][rr] + bvv;
        size_t idx = (size_t)m * N + n;
        if (epi == 0) { if (z < 2) v = v * v; outz[idx] = f2bf(v); }
        else if (epi == 1) { v = 0.5f * v * (1.0f + erff(v * 0.70710678118654752f)); outz[idx] = f2bf(v); }
        else { outf[idx] = outf[idx] + v; }
      }
    }
  }
}

// ---------------- attention A1: per (b,h,chunk) S_c = K^T V, z_c = sum k ------
// stores St[d][f] (transposed) and Zc[f], both fp32
__global__ __launch_bounds__(64) void attn_chunk_kv(
    const short* __restrict__ Kb, const short* __restrict__ Vb,
    float* __restrict__ St, float* __restrict__ Zc) {
  __shared__ short Kt[32 * 72];  // [f][t] padded
  __shared__ short Vt[32 * 72];  // [d][t]
  int blk = blockIdx.x;
  int c = blk & (NC - 1), bh = blk >> 5;
  int b = bh >> 3, hh = bh & 7;
  int lane = threadIdx.x, q = lane >> 4, r = lane & 15;
  size_t rowbase = ((size_t)(b * GG + c * CS + lane)) * DD + hh * HD;
#pragma unroll
  for (int j = 0; j < 4; ++j) {
    bf16x8 kv = *(const bf16x8*)&Kb[rowbase + j * 8];
    bf16x8 vv = *(const bf16x8*)&Vb[rowbase + j * 8];
#pragma unroll
    for (int e = 0; e < 8; ++e) {
      Kt[(j * 8 + e) * 72 + lane] = kv[e];
      Vt[(j * 8 + e) * 72 + lane] = vv[e];
    }
  }
  __syncthreads();
  f32x4 vzero = {0.f, 0.f, 0.f, 0.f};
  f32x4 acc[2][2];
#pragma unroll
  for (int i = 0; i < 2; ++i)
#pragma unroll
    for (int j = 0; j < 2; ++j) acc[i][j] = vzero;
#pragma unroll
  for (int ks = 0; ks < 2; ++ks) {
    bf16x8 afr[2], bfr[2];
#pragma unroll
    for (int mt = 0; mt < 2; ++mt) afr[mt] = *(const bf16x8*)&Kt[(mt * 16 + r) * 72 + ks * 32 + q * 8];
#pragma unroll
    for (int nt = 0; nt < 2; ++nt) bfr[nt] = *(const bf16x8*)&Vt[(nt * 16 + r) * 72 + ks * 32 + q * 8];
#pragma unroll
    for (int mt = 0; mt < 2; ++mt)
#pragma unroll
      for (int nt = 0; nt < 2; ++nt)
        acc[mt][nt] = __builtin_amdgcn_mfma_f32_16x16x32_bf16(afr[mt], bfr[nt], acc[mt][nt], 0, 0, 0);
  }
  float* stp = St + ((size_t)bh * NC + c) * 1024;
#pragma unroll
  for (int mt = 0; mt < 2; ++mt)
#pragma unroll
    for (int nt = 0; nt < 2; ++nt)
      *(f32x4*)&stp[(nt * 16 + r) * 32 + mt * 16 + q * 4] = acc[mt][nt];  // St[d][f]
  if (lane < 32) {
    float s = 0.f;
#pragma unroll
    for (int j = 0; j < 8; ++j) {
      bf16x8 kr = *(const bf16x8*)&Kt[lane * 72 + j * 8];
#pragma unroll
      for (int e = 0; e < 8; ++e) s += bf2f(kr[e]);
    }
    Zc[((size_t)bh * NC + c) * 32 + lane] = s;
  }
}

// ---------------- attention A2: exclusive prefix over chunks ------------------
__global__ __launch_bounds__(1024) void attn_prefix(float* __restrict__ St, float* __restrict__ Zc) {
  int bh = blockIdx.x, i = threadIdx.x;
  float run = 0.f;
  float* p = St + (size_t)bh * NC * 1024 + i;
#pragma unroll
  for (int c = 0; c < NC; ++c) { float t = p[(size_t)c * 1024]; p[(size_t)c * 1024] = run; run += t; }
  if (i < 32) {
    float rz = 0.f;
    float* pz = Zc + (size_t)bh * NC * 32 + i;
#pragma unroll
    for (int c = 0; c < NC; ++c) { float t = pz[c * 32]; pz[c * 32] = rz; rz += t; }
  }
}

// ---------------- attention B: intra-chunk + apply, h += out ------------------
__global__ __launch_bounds__(64) void attn_intra(
    const short* __restrict__ Qb, const short* __restrict__ Kb,
    const short* __restrict__ Vb, const float* __restrict__ St,
    const float* __restrict__ Zc, float* __restrict__ h) {
  __shared__ short P[64 * 72];   // [t][s] bf16, padded
  __shared__ short Vt[32 * 72];  // [d][t]
  __shared__ float den[64];
  int blk = blockIdx.x;
  int c = blk & (NC - 1), bh = blk >> 5;
  int b = bh >> 3, hh = bh & 7;
  int lane = threadIdx.x, q = lane >> 4, r = lane & 15;
  size_t row0 = (size_t)b * GG + c * CS;

  // q . z_prefix (lane = t)
  const float* zp = Zc + ((size_t)bh * NC + c) * 32;
  float qz = 0.f;
  {
    size_t qoff = (row0 + lane) * DD + hh * HD;
#pragma unroll
    for (int j = 0; j < 4; ++j) {
      bf16x8 qv = *(const bf16x8*)&Qb[qoff + j * 8];
#pragma unroll
      for (int e = 0; e < 8; ++e) qz += bf2f(qv[e]) * zp[j * 8 + e];
    }
  }
  den[lane] = qz;

  // stage V^T (lane = s)
  {
    size_t voff = (row0 + lane) * DD + hh * HD;
#pragma unroll
    for (int j = 0; j < 4; ++j) {
      bf16x8 vv = *(const bf16x8*)&Vb[voff + j * 8];
#pragma unroll
      for (int e = 0; e < 8; ++e) Vt[(j * 8 + e) * 72 + lane] = vv[e];
    }
  }

  // P^T = K Q^T  (D[m=s][n=t]); frags straight from global (row-contiguous)
  bf16x8 ak[4], bqf[4];
#pragma unroll
  for (int t4 = 0; t4 < 4; ++t4) {
    ak[t4]  = *(const bf16x8*)&Kb[(row0 + t4 * 16 + r) * DD + hh * HD + q * 8];
    bqf[t4] = *(const bf16x8*)&Qb[(row0 + t4 * 16 + r) * DD + hh * HD + q * 8];
  }
  f32x4 vzero = {0.f, 0.f, 0.f, 0.f};
  f32x4 pacc[4][4];
#pragma unroll
  for (int mt = 0; mt < 4; ++mt)
#pragma unroll
    for (int nt = 0; nt < 4; ++nt)
      pacc[mt][nt] = __builtin_amdgcn_mfma_f32_16x16x32_bf16(ak[mt], bqf[nt], vzero, 0, 0, 0);

  // mask (s<=t), rowsum partials, pack bf16 into P[t][s]
  float rs[4] = {0.f, 0.f, 0.f, 0.f};
#pragma unroll
  for (int nt = 0; nt < 4; ++nt) {
    int t = nt * 16 + r;
#pragma unroll
    for (int mt = 0; mt < 4; ++mt) {
      short4 pk;
#pragma unroll
      for (int rr = 0; rr < 4; ++rr) {
        int s = mt * 16 + q * 4 + rr;
        float pv = (s <= t) ? pacc[mt][nt][rr] : 0.f;
        rs[nt] += pv;
        ((short*)&pk)[rr] = f2bf(pv);
      }
      *(short4*)&P[t * 72 + mt * 16 + q * 4] = pk;
    }
  }
#pragma unroll
  for (int nt = 0; nt < 4; ++nt) {
    rs[nt] += __shfl_xor(rs[nt], 16);
    rs[nt] += __shfl_xor(rs[nt], 32);
  }
  __syncthreads();
  if (lane < 16) {
#pragma unroll
    for (int nt = 0; nt < 4; ++nt) den[nt * 16 + lane] += rs[nt];
  }
  __syncthreads();

  // OUT = Q*S_pref + P*V   (D[m=t][n=d])
  f32x4 oacc[4][2];
#pragma unroll
  for (int mt = 0; mt < 4; ++mt)
#pragma unroll
    for (int nt2 = 0; nt2 < 2; ++nt2) oacc[mt][nt2] = vzero;
  const float* stp = St + ((size_t)bh * NC + c) * 1024;
#pragma unroll
  for (int nt2 = 0; nt2 < 2; ++nt2) {
    float4 s0 = *(const float4*)&stp[(nt2 * 16 + r) * 32 + q * 8];
    float4 s1 = *(const float4*)&stp[(nt2 * 16 + r) * 32 + q * 8 + 4];
    bf16x8 bs;
    bs[0] = f2bf(s0.x); bs[1] = f2bf(s0.y); bs[2] = f2bf(s0.z); bs[3] = f2bf(s0.w);
    bs[4] = f2bf(s1.x); bs[5] = f2bf(s1.y); bs[6] = f2bf(s1.z); bs[7] = f2bf(s1.w);
#pragma unroll
    for (int mt = 0; mt < 4; ++mt)
      oacc[mt][nt2] = __builtin_amdgcn_mfma_f32_16x16x32_bf16(bqf[mt], bs, oacc[mt][nt2], 0, 0, 0);
  }
#pragma unroll
  for (int ks = 0; ks < 2; ++ks) {
    bf16x8 ap[4];
#pragma unroll
    for (int mt = 0; mt < 4; ++mt)
      ap[mt] = *(const bf16x8*)&P[(mt * 16 + r) * 72 + ks * 32 + q * 8];
#pragma unroll
    for (int nt2 = 0; nt2 < 2; ++nt2) {
      bf16x8 bv_ = *(const bf16x8*)&Vt[(nt2 * 16 + r) * 72 + ks * 32 + q * 8];
#pragma unroll
      for (int mt = 0; mt < 4; ++mt)
        oacc[mt][nt2] = __builtin_amdgcn_mfma_f32_16x16x32_bf16(ap[mt], bv_, oacc[mt][nt2], 0, 0, 0);
    }
  }

  // h += out/den
#pragma unroll
  for (int mt = 0; mt < 4; ++mt) {
#pragma unroll
    for (int rr = 0; rr < 4; ++rr) {
      int t = mt * 16 + q * 4 + rr;
      float inv = 1.0f / (den[t] + 1e-16f);
#pragma unroll
      for (int nt2 = 0; nt2 < 2; ++nt2) {
        int d = nt2 * 16 + r;
        size_t off = (row0 + t) * DD + hh * HD + d;
        h[off] += oacc[mt][nt2][rr] * inv;
      }
    }
  }
}

// ---------------- final projection: out = h @ Wout + bout ---------------------
__global__ __launch_bounds__(64) void out_proj(
    const float* __restrict__ h, const float* __restrict__ Wout,
    const float* __restrict__ bout, float* __restrict__ out) {
  int row = blockIdx.x, lane = threadIdx.x;
  float4 a = *(const float4*)&h[(size_t)row * DD + lane * 4];
  float4 w = *(const float4*)&Wout[lane * 4];
  float s = a.x * w.x + a.y * w.y + a.z * w.z + a.w * w.w;
#pragma unroll
  for (int o = 1; o < 64; o <<= 1) s += __shfl_xor(s, o);
  if (lane == 0) out[row] = s + bout[0];
}

extern "C" void kernel_launch(void* const* d_in, const int* in_sizes, int n_in,
                              void* d_out, int out_size, void* d_ws, size_t ws_size,
                              hipStream_t stream) {
  const float* x    = (const float*)d_in[0];
  const float* ge   = (const float*)d_in[1];
  const float* invf = (const float*)d_in[2];
  const float* Wq   = (const float*)d_in[3];
  const float* bq   = (const float*)d_in[4];
  const float* Wk   = (const float*)d_in[5];
  const float* bk   = (const float*)d_in[6];
  const float* Wv   = (const float*)d_in[7];
  const float* bv   = (const float*)d_in[8];
  const float* ln1g = (const float*)d_in[9];
  const float* ln1b = (const float*)d_in[10];
  const float* ln2g = (const float*)d_in[11];
  const float* ln2b = (const float*)d_in[12];
  const float* WU   = (const float*)d_in[13];
  const float* bU   = (const float*)d_in[14];
  const float* WV   = (const float*)d_in[15];
  const float* bV   = (const float*)d_in[16];
  const float* Wout = (const float*)d_in[17];
  const float* bout = (const float*)d_in[18];
  float* out = (float*)d_out;

  // workspace layout (total ~123.8 MB)
  char* ws = (char*)d_ws;
  float* h   = (float*)(ws + 0);            // 33.5 MB
  short* hn  = (short*)(ws + 33554432);     // 16.8 MB
  char*  R   = ws + 50331648;               // shared region 67.6 MB
  short* qb  = (short*)(R + 0);             // 16.8 MB  (overlaps mid, disjoint in time)
  short* kb  = (short*)(R + 16777216);
  short* vb  = (short*)(R + 33554432);
  float* St  = (float*)(R + 50331648);      // 16.8 MB
  float* Zc  = (float*)(R + 67108864);      // 0.5 MB
  short* mid = (short*)(R + 0);             // 67.1 MB (FFN phase)
  char*  WT  = R + 67633152;                // 5.8 MB bf16 transposed weights
  short* TQ  = (short*)(WT + 0);
  short* TK  = (short*)(WT + 524288);
  short* TVq = (short*)(WT + 1048576);
  short* TU  = (short*)(WT + 1572864);
  short* TVd = (short*)(WT + 3670016);

  prep_weights<<<dim3(1024, 4, 5), 256, 0, stream>>>(Wq, Wk, Wv, WU, WV, TQ, TK, TVq, TU, TVd);
  embed_kernel<<<NROWS, 64, 0, stream>>>(x, ge, invf, h);

  for (int l = 0; l < 4; ++l) {
    ln_kernel<<<NROWS, 64, 0, stream>>>(h, ln1g + l * 256, ln1b + l * 256, hn);
    gemm_bf16<<<dim3(256, 2, 3), 256, 0, stream>>>(
        hn, TQ + l * 65536, TK + l * 65536, TVq + l * 65536,
        bq + l * 256, bk + l * 256, bv + l * 256,
        qb, kb, vb, nullptr, 256, 256, 0);
    attn_chunk_kv<<<4096, 64, 0, stream>>>(kb, vb, St, Zc);
    attn_prefix<<<128, 1024, 0, stream>>>(St, Zc);
    attn_intra<<<4096, 64, 0, stream>>>(qb, kb, vb, St, Zc, h);
    ln_kernel<<<NROWS, 64, 0, stream>>>(h, ln2g + l * 256, ln2b + l * 256, hn);
    gemm_bf16<<<dim3(256, 8, 1), 256, 0, stream>>>(
        hn, TU + l * 262144, nullptr, nullptr,
        bU + l * 1024, nullptr, nullptr,
        mid, nullptr, nullptr, nullptr, 1024, 256, 1);
    gemm_bf16<<<dim3(256, 2, 1), 256, 0, stream>>>(
        mid, TVd + l * 262144, nullptr, nullptr,
        bV + l * 256, nullptr, nullptr,
        nullptr, nullptr, nullptr, h, 256, 1024, 2);
  }
  out_proj<<<NROWS, 64, 0, stream>>>(h, Wout, bout, out);
}

// Round 2
// 929.634 us; speedup vs baseline: 1.1138x; 1.1138x over previous
//
#include <hip/hip_runtime.h>
#include <math.h>

// ExpressionPerformer: B=16,G=2048,D=256,H=8,dh=32,FFN=1024,L=4
// Round-2 changes:
//  - gemm: global_load_lds width=16 staging (no VGPR round-trip)
//  - gemm: swapped MFMA operands -> transposed C layout -> packed short4/float4
//    epilogue stores (fixes 1.87x HBM write amplification)
//  - ln/embed/out_proj batched 4 rows per 256-thread block

#define GG 2048
#define DD 256
#define HD 32
#define NROWS 32768
#define NC 32
#define CS 64

typedef __attribute__((ext_vector_type(8))) short bf16x8;
typedef __attribute__((ext_vector_type(4))) float f32x4;

__device__ __forceinline__ short f2bf(float f) {
  union { float f; unsigned u; } v; v.f = f;
  unsigned r = v.u + 0x7FFFu + ((v.u >> 16) & 1u);
  return (short)(r >> 16);
}
__device__ __forceinline__ float bf2f(short s) {
  union { unsigned u; float f; } v; v.u = ((unsigned)(unsigned short)s) << 16;
  return v.f;
}
__device__ __forceinline__ void gld16(const short* g, short* l) {
  __builtin_amdgcn_global_load_lds(
      (const __attribute__((address_space(1))) void*)g,
      (__attribute__((address_space(3))) void*)l, 16, 0, 0);
}

// ---------------- embed: h = gene_emb + [sin(x*invf), cos(x*invf)] (masked) ----
__global__ __launch_bounds__(256) void embed_kernel(
    const float* __restrict__ x, const float* __restrict__ ge,
    const float* __restrict__ invf, float* __restrict__ h) {
  int bg = blockIdx.x * 4 + (threadIdx.x >> 6);
  int g = bg & (GG - 1);
  int lane = threadIdx.x & 63;
  float xv = x[bg];
  int d = lane * 4;
  float4 e;
  if (lane < 32) {
    float4 f = *(const float4*)&invf[d];
    e.x = sinf(xv * f.x); e.y = sinf(xv * f.y);
    e.z = sinf(xv * f.z); e.w = sinf(xv * f.w);
  } else {
    float4 f = *(const float4*)&invf[d - 128];
    e.x = cosf(xv * f.x); e.y = cosf(xv * f.y);
    e.z = cosf(xv * f.z); e.w = cosf(xv * f.w);
  }
  if (xv == -10.0f) { e.x = 0.f; e.y = 0.f; e.z = 0.f; e.w = 0.f; }
  float4 gv = *(const float4*)&ge[(size_t)g * DD + d];
  float4 o; o.x = gv.x + e.x; o.y = gv.y + e.y; o.z = gv.z + e.z; o.w = gv.w + e.w;
  *(float4*)&h[(size_t)bg * DD + d] = o;
}

// ---------------- layernorm (row of 256) -> bf16, 4 rows/block ----------------
__global__ __launch_bounds__(256) void ln_kernel(
    const float* __restrict__ h, const float* __restrict__ gamma,
    const float* __restrict__ beta, short* __restrict__ out) {
  int row = blockIdx.x * 4 + (threadIdx.x >> 6);
  int lane = threadIdx.x & 63;
  float4 xv = *(const float4*)&h[(size_t)row * DD + lane * 4];
  float s = xv.x + xv.y + xv.z + xv.w;
#pragma unroll
  for (int o = 1; o < 64; o <<= 1) s += __shfl_xor(s, o);
  float mean = s * (1.0f / 256.0f);
  float a = xv.x - mean, b = xv.y - mean, c = xv.z - mean, d = xv.w - mean;
  float s2 = a * a + b * b + c * c + d * d;
#pragma unroll
  for (int o = 1; o < 64; o <<= 1) s2 += __shfl_xor(s2, o);
  float rstd = rsqrtf(s2 * (1.0f / 256.0f) + 1e-5f);
  float4 g = *(const float4*)&gamma[lane * 4];
  float4 bb = *(const float4*)&beta[lane * 4];
  short4 o4;
  o4.x = f2bf(a * rstd * g.x + bb.x);
  o4.y = f2bf(b * rstd * g.y + bb.y);
  o4.z = f2bf(c * rstd * g.z + bb.z);
  o4.w = f2bf(d * rstd * g.w + bb.w);
  *(short4*)&out[(size_t)row * DD + lane * 4] = o4;
}

// ---------------- weight convert+transpose: W[K][N] -> WT[N][K] bf16 ----------
__global__ __launch_bounds__(256) void prep_weights(
    const float* __restrict__ Wq, const float* __restrict__ Wk,
    const float* __restrict__ Wv, const float* __restrict__ WU,
    const float* __restrict__ WV,
    short* __restrict__ TQ, short* __restrict__ TK, short* __restrict__ TV,
    short* __restrict__ TU, short* __restrict__ TVd) {
  int zz = blockIdx.z, l = blockIdx.y;
  const float* src; short* dst; int Kd, Nd;
  if (zz == 0) { src = Wq; dst = TQ; Kd = 256; Nd = 256; }
  else if (zz == 1) { src = Wk; dst = TK; Kd = 256; Nd = 256; }
  else if (zz == 2) { src = Wv; dst = TV; Kd = 256; Nd = 256; }
  else if (zz == 3) { src = WU; dst = TU; Kd = 256; Nd = 1024; }
  else { src = WV; dst = TVd; Kd = 1024; Nd = 256; }
  int tot = Kd * Nd;
  int e = blockIdx.x * 256 + threadIdx.x;
  if (e >= tot) return;
  int n = e / Kd, k = e - n * Kd;
  dst[(size_t)l * tot + e] = f2bf(src[(size_t)l * tot + (size_t)k * Nd + n]);
}

// ---------------- bf16 MFMA GEMM: C = A[M,K] * BT[N,K]^T + bias ---------------
// Swapped-operand MFMA: acc[mt][nt] holds C^T fragment => lane owns 4 consecutive n.
// epi 0: z<2 -> square, bf16 out (QKV);  1: gelu, bf16 out;  2: h += acc+bias
__global__ __launch_bounds__(256) void gemm_bf16(
    const short* __restrict__ A, const short* __restrict__ B0,
    const short* __restrict__ B1, const short* __restrict__ B2,
    const float* __restrict__ bias0, const float* __restrict__ bias1,
    const float* __restrict__ bias2,
    short* __restrict__ o0, short* __restrict__ o1, short* __restrict__ o2,
    float* __restrict__ outf, int N, int K, int epi) {
  __shared__ short As[4096];  // 128x32 bf16, 16B-chunk-major [kb][m]
  __shared__ short Bs[4096];  // 128x32 bf16 (rows of BT), chunk-major [kb][n]
  int z = blockIdx.z;
  const short* Bt = (z == 0) ? B0 : (z == 1) ? B1 : B2;
  const float* bias = (z == 0) ? bias0 : (z == 1) ? bias1 : bias2;
  short* outz = (z == 0) ? o0 : (z == 1) ? o1 : o2;
  int m0 = blockIdx.x * 128, n0 = blockIdx.y * 128;
  int tid = threadIdx.x;
  int lane = tid & 63, w = tid >> 6;
  int q = lane >> 4, r = lane & 15;
  int wm = (w >> 1) * 64, wn = (w & 1) * 64;
  f32x4 vzero = {0.f, 0.f, 0.f, 0.f};
  f32x4 acc[4][4];
#pragma unroll
  for (int i = 0; i < 4; ++i)
#pragma unroll
    for (int j = 0; j < 4; ++j) acc[i][j] = vzero;

  int c0 = tid, c1 = tid + 256;
  const short* a0 = &A[(size_t)(m0 + (c0 & 127)) * K + (c0 >> 7) * 8];
  const short* a1 = &A[(size_t)(m0 + (c1 & 127)) * K + (c1 >> 7) * 8];
  const short* b0p = &Bt[(size_t)(n0 + (c0 & 127)) * K + (c0 >> 7) * 8];
  const short* b1p = &Bt[(size_t)(n0 + (c1 & 127)) * K + (c1 >> 7) * 8];

  for (int k0 = 0; k0 < K; k0 += 32) {
    __syncthreads();
    gld16(a0 + k0, &As[c0 * 8]);
    gld16(a1 + k0, &As[c1 * 8]);
    gld16(b0p + k0, &Bs[c0 * 8]);
    gld16(b1p + k0, &Bs[c1 * 8]);
    __syncthreads();
    bf16x8 af[4], bfr[4];
#pragma unroll
    for (int mt = 0; mt < 4; ++mt)
      af[mt] = *(const bf16x8*)&As[(q * 128 + wm + mt * 16 + r) * 8];
#pragma unroll
    for (int nt = 0; nt < 4; ++nt)
      bfr[nt] = *(const bf16x8*)&Bs[(q * 128 + wn + nt * 16 + r) * 8];
#pragma unroll
    for (int mt = 0; mt < 4; ++mt)
#pragma unroll
      for (int nt = 0; nt < 4; ++nt)
        acc[mt][nt] = __builtin_amdgcn_mfma_f32_16x16x32_bf16(bfr[nt], af[mt], acc[mt][nt], 0, 0, 0);
  }

  // epilogue: lane (q,r) in tile (mt,nt): m = wm+mt*16+r, n = wn+nt*16+q*4+[0..3]
  float4 bias4[4];
#pragma unroll
  for (int nt = 0; nt < 4; ++nt) bias4[nt] = *(const float4*)&bias[n0 + wn + nt * 16 + q * 4];
#pragma unroll
  for (int mt = 0; mt < 4; ++mt) {
    int m = m0 + wm + mt * 16 + r;
    size_t rowoff = (size_t)m * N + n0 + wn + q * 4;
#pragma unroll
    for (int nt = 0; nt < 4; ++nt) {
      f32x4 v = acc[mt][nt];
      v[0] += bias4[nt].x; v[1] += bias4[nt].y; v[2] += bias4[nt].z; v[3] += bias4[nt].w;
      if (epi == 0) {
        if (z < 2) { v[0] *= v[0]; v[1] *= v[1]; v[2] *= v[2]; v[3] *= v[3]; }
        short4 o; o.x = f2bf(v[0]); o.y = f2bf(v[1]); o.z = f2bf(v[2]); o.w = f2bf(v[3]);
        *(short4*)&outz[rowoff + nt * 16] = o;
      } else if (epi == 1) {
#pragma unroll
        for (int e = 0; e < 4; ++e) v[e] = 0.5f * v[e] * (1.0f + erff(v[e] * 0.70710678118654752f));
        short4 o; o.x = f2bf(v[0]); o.y = f2bf(v[1]); o.z = f2bf(v[2]); o.w = f2bf(v[3]);
        *(short4*)&outz[rowoff + nt * 16] = o;
      } else {
        float4 cur = *(float4*)&outf[rowoff + nt * 16];
        cur.x += v[0]; cur.y += v[1]; cur.z += v[2]; cur.w += v[3];
        *(float4*)&outf[rowoff + nt * 16] = cur;
      }
    }
  }
}

// ---------------- attention A1: per (b,h,chunk) S_c = K^T V, z_c = sum k ------
__global__ __launch_bounds__(64) void attn_chunk_kv(
    const short* __restrict__ Kb, const short* __restrict__ Vb,
    float* __restrict__ St, float* __restrict__ Zc) {
  __shared__ short Kt[32 * 72];  // [f][t] padded
  __shared__ short Vt[32 * 72];  // [d][t]
  int blk = blockIdx.x;
  int c = blk & (NC - 1), bh = blk >> 5;
  int b = bh >> 3, hh = bh & 7;
  int lane = threadIdx.x, q = lane >> 4, r = lane & 15;
  size_t rowbase = ((size_t)(b * GG + c * CS + lane)) * DD + hh * HD;
#pragma unroll
  for (int j = 0; j < 4; ++j) {
    bf16x8 kv = *(const bf16x8*)&Kb[rowbase + j * 8];
    bf16x8 vv = *(const bf16x8*)&Vb[rowbase + j * 8];
#pragma unroll
    for (int e = 0; e < 8; ++e) {
      Kt[(j * 8 + e) * 72 + lane] = kv[e];
      Vt[(j * 8 + e) * 72 + lane] = vv[e];
    }
  }
  __syncthreads();
  f32x4 vzero = {0.f, 0.f, 0.f, 0.f};
  f32x4 acc[2][2];
#pragma unroll
  for (int i = 0; i < 2; ++i)
#pragma unroll
    for (int j = 0; j < 2; ++j) acc[i][j] = vzero;
#pragma unroll
  for (int ks = 0; ks < 2; ++ks) {
    bf16x8 afr[2], bfr[2];
#pragma unroll
    for (int mt = 0; mt < 2; ++mt) afr[mt] = *(const bf16x8*)&Kt[(mt * 16 + r) * 72 + ks * 32 + q * 8];
#pragma unroll
    for (int nt = 0; nt < 2; ++nt) bfr[nt] = *(const bf16x8*)&Vt[(nt * 16 + r) * 72 + ks * 32 + q * 8];
#pragma unroll
    for (int mt = 0; mt < 2; ++mt)
#pragma unroll
      for (int nt = 0; nt < 2; ++nt)
        acc[mt][nt] = __builtin_amdgcn_mfma_f32_16x16x32_bf16(afr[mt], bfr[nt], acc[mt][nt], 0, 0, 0);
  }
  float* stp = St + ((size_t)bh * NC + c) * 1024;
#pragma unroll
  for (int mt = 0; mt < 2; ++mt)
#pragma unroll
    for (int nt = 0; nt < 2; ++nt)
      *(f32x4*)&stp[(nt * 16 + r) * 32 + mt * 16 + q * 4] = acc[mt][nt];  // St[d][f]
  if (lane < 32) {
    float s = 0.f;
#pragma unroll
    for (int j = 0; j < 8; ++j) {
      bf16x8 kr = *(const bf16x8*)&Kt[lane * 72 + j * 8];
#pragma unroll
      for (int e = 0; e < 8; ++e) s += bf2f(kr[e]);
    }
    Zc[((size_t)bh * NC + c) * 32 + lane] = s;
  }
}

// ---------------- attention A2: exclusive prefix over chunks ------------------
__global__ __launch_bounds__(1024) void attn_prefix(float* __restrict__ St, float* __restrict__ Zc) {
  int bh = blockIdx.x, i = threadIdx.x;
  float run = 0.f;
  float* p = St + (size_t)bh * NC * 1024 + i;
#pragma unroll
  for (int c = 0; c < NC; ++c) { float t = p[(size_t)c * 1024]; p[(size_t)c * 1024] = run; run += t; }
  if (i < 32) {
    float rz = 0.f;
    float* pz = Zc + (size_t)bh * NC * 32 + i;
#pragma unroll
    for (int c = 0; c < NC; ++c) { float t = pz[c * 32]; pz[c * 32] = rz; rz += t; }
  }
}

// ---------------- attention B: intra-chunk + apply, h += out ------------------
__global__ __launch_bounds__(64) void attn_intra(
    const short* __restrict__ Qb, const short* __restrict__ Kb,
    const short* __restrict__ Vb, const float* __restrict__ St,
    const float* __restrict__ Zc, float* __restrict__ h) {
  __shared__ short P[64 * 72];   // [t][s] bf16, padded
  __shared__ short Vt[32 * 72];  // [d][t]
  __shared__ float den[64];
  int blk = blockIdx.x;
  int c = blk & (NC - 1), bh = blk >> 5;
  int b = bh >> 3, hh = bh & 7;
  int lane = threadIdx.x, q = lane >> 4, r = lane & 15;
  size_t row0 = (size_t)b * GG + c * CS;

  const float* zp = Zc + ((size_t)bh * NC + c) * 32;
  float qz = 0.f;
  {
    size_t qoff = (row0 + lane) * DD + hh * HD;
#pragma unroll
    for (int j = 0; j < 4; ++j) {
      bf16x8 qv = *(const bf16x8*)&Qb[qoff + j * 8];
#pragma unroll
      for (int e = 0; e < 8; ++e) qz += bf2f(qv[e]) * zp[j * 8 + e];
    }
  }
  den[lane] = qz;

  {
    size_t voff = (row0 + lane) * DD + hh * HD;
#pragma unroll
    for (int j = 0; j < 4; ++j) {
      bf16x8 vv = *(const bf16x8*)&Vb[voff + j * 8];
#pragma unroll
      for (int e = 0; e < 8; ++e) Vt[(j * 8 + e) * 72 + lane] = vv[e];
    }
  }

  bf16x8 ak[4], bqf[4];
#pragma unroll
  for (int t4 = 0; t4 < 4; ++t4) {
    ak[t4]  = *(const bf16x8*)&Kb[(row0 + t4 * 16 + r) * DD + hh * HD + q * 8];
    bqf[t4] = *(const bf16x8*)&Qb[(row0 + t4 * 16 + r) * DD + hh * HD + q * 8];
  }
  f32x4 vzero = {0.f, 0.f, 0.f, 0.f};
  f32x4 pacc[4][4];
#pragma unroll
  for (int mt = 0; mt < 4; ++mt)
#pragma unroll
    for (int nt = 0; nt < 4; ++nt)
      pacc[mt][nt] = __builtin_amdgcn_mfma_f32_16x16x32_bf16(ak[mt], bqf[nt], vzero, 0, 0, 0);

  float rs[4] = {0.f, 0.f, 0.f, 0.f};
#pragma unroll
  for (int nt = 0; nt < 4; ++nt) {
    int t = nt * 16 + r;
#pragma unroll
    for (int mt = 0; mt < 4; ++mt) {
      short4 pk;
#pragma unroll
      for (int rr = 0; rr < 4; ++rr) {
        int s = mt * 16 + q * 4 + rr;
        float pv = (s <= t) ? pacc[mt][nt][rr] : 0.f;
        rs[nt] += pv;
        ((short*)&pk)[rr] = f2bf(pv);
      }
      *(short4*)&P[t * 72 + mt * 16 + q * 4] = pk;
    }
  }
#pragma unroll
  for (int nt = 0; nt < 4; ++nt) {
    rs[nt] += __shfl_xor(rs[nt], 16);
    rs[nt] += __shfl_xor(rs[nt], 32);
  }
  __syncthreads();
  if (lane < 16) {
#pragma unroll
    for (int nt = 0; nt < 4; ++nt) den[nt * 16 + lane] += rs[nt];
  }
  __syncthreads();

  f32x4 oacc[4][2];
#pragma unroll
  for (int mt = 0; mt < 4; ++mt)
#pragma unroll
    for (int nt2 = 0; nt2 < 2; ++nt2) oacc[mt][nt2] = vzero;
  const float* stp = St + ((size_t)bh * NC + c) * 1024;
#pragma unroll
  for (int nt2 = 0; nt2 < 2; ++nt2) {
    float4 s0 = *(const float4*)&stp[(nt2 * 16 + r) * 32 + q * 8];
    float4 s1 = *(const float4*)&stp[(nt2 * 16 + r) * 32 + q * 8 + 4];
    bf16x8 bs;
    bs[0] = f2bf(s0.x); bs[1] = f2bf(s0.y); bs[2] = f2bf(s0.z); bs[3] = f2bf(s0.w);
    bs[4] = f2bf(s1.x); bs[5] = f2bf(s1.y); bs[6] = f2bf(s1.z); bs[7] = f2bf(s1.w);
#pragma unroll
    for (int mt = 0; mt < 4; ++mt)
      oacc[mt][nt2] = __builtin_amdgcn_mfma_f32_16x16x32_bf16(bqf[mt], bs, oacc[mt][nt2], 0, 0, 0);
  }
#pragma unroll
  for (int ks = 0; ks < 2; ++ks) {
    bf16x8 ap[4];
#pragma unroll
    for (int mt = 0; mt < 4; ++mt)
      ap[mt] = *(const bf16x8*)&P[(mt * 16 + r) * 72 + ks * 32 + q * 8];
#pragma unroll
    for (int nt2 = 0; nt2 < 2; ++nt2) {
      bf16x8 bv_ = *(const bf16x8*)&Vt[(nt2 * 16 + r) * 72 + ks * 32 + q * 8];
#pragma unroll
      for (int mt = 0; mt < 4; ++mt)
        oacc[mt][nt2] = __builtin_amdgcn_mfma_f32_16x16x32_bf16(ap[mt], bv_, oacc[mt][nt2], 0, 0, 0);
    }
  }

#pragma unroll
  for (int mt = 0; mt < 4; ++mt) {
#pragma unroll
    for (int rr = 0; rr < 4; ++rr) {
      int t = mt * 16 + q * 4 + rr;
      float inv = 1.0f / (den[t] + 1e-16f);
#pragma unroll
      for (int nt2 = 0; nt2 < 2; ++nt2) {
        int d = nt2 * 16 + r;
        size_t off = (row0 + t) * DD + hh * HD + d;
        h[off] += oacc[mt][nt2][rr] * inv;
      }
    }
  }
}

// ---------------- final projection: out = h @ Wout + bout ---------------------
__global__ __launch_bounds__(256) void out_proj(
    const float* __restrict__ h, const float* __restrict__ Wout,
    const float* __restrict__ bout, float* __restrict__ out) {
  int row = blockIdx.x * 4 + (threadIdx.x >> 6);
  int lane = threadIdx.x & 63;
  float4 a = *(const float4*)&h[(size_t)row * DD + lane * 4];
  float4 w = *(const float4*)&Wout[lane * 4];
  float s = a.x * w.x + a.y * w.y + a.z * w.z + a.w * w.w;
#pragma unroll
  for (int o = 1; o < 64; o <<= 1) s += __shfl_xor(s, o);
  if (lane == 0) out[row] = s + bout[0];
}

extern "C" void kernel_launch(void* const* d_in, const int* in_sizes, int n_in,
                              void* d_out, int out_size, void* d_ws, size_t ws_size,
                              hipStream_t stream) {
  const float* x    = (const float*)d_in[0];
  const float* ge   = (const float*)d_in[1];
  const float* invf = (const float*)d_in[2];
  const float* Wq   = (const float*)d_in[3];
  const float* bq   = (const float*)d_in[4];
  const float* Wk   = (const float*)d_in[5];
  const float* bk   = (const float*)d_in[6];
  const float* Wv   = (const float*)d_in[7];
  const float* bv   = (const float*)d_in[8];
  const float* ln1g = (const float*)d_in[9];
  const float* ln1b = (const float*)d_in[10];
  const float* ln2g = (const float*)d_in[11];
  const float* ln2b = (const float*)d_in[12];
  const float* WU   = (const float*)d_in[13];
  const float* bU   = (const float*)d_in[14];
  const float* WV   = (const float*)d_in[15];
  const float* bV   = (const float*)d_in[16];
  const float* Wout = (const float*)d_in[17];
  const float* bout = (const float*)d_in[18];
  float* out = (float*)d_out;

  char* ws = (char*)d_ws;
  float* h   = (float*)(ws + 0);            // 33.5 MB
  short* hn  = (short*)(ws + 33554432);     // 16.8 MB
  char*  R   = ws + 50331648;               // shared region
  short* qb  = (short*)(R + 0);
  short* kb  = (short*)(R + 16777216);
  short* vb  = (short*)(R + 33554432);
  float* St  = (float*)(R + 50331648);
  float* Zc  = (float*)(R + 67108864);
  short* mid = (short*)(R + 0);             // FFN phase (overlaps q/k/v in time)
  char*  WT  = R + 67633152;
  short* TQ  = (short*)(WT + 0);
  short* TK  = (short*)(WT + 524288);
  short* TVq = (short*)(WT + 1048576);
  short* TU  = (short*)(WT + 1572864);
  short* TVd = (short*)(WT + 3670016);

  prep_weights<<<dim3(1024, 4, 5), 256, 0, stream>>>(Wq, Wk, Wv, WU, WV, TQ, TK, TVq, TU, TVd);
  embed_kernel<<<NROWS / 4, 256, 0, stream>>>(x, ge, invf, h);

  for (int l = 0; l < 4; ++l) {
    ln_kernel<<<NROWS / 4, 256, 0, stream>>>(h, ln1g + l * 256, ln1b + l * 256, hn);
    gemm_bf16<<<dim3(256, 2, 3), 256, 0, stream>>>(
        hn, TQ + l * 65536, TK + l * 65536, TVq + l * 65536,
        bq + l * 256, bk + l * 256, bv + l * 256,
        qb, kb, vb, nullptr, 256, 256, 0);
    attn_chunk_kv<<<4096, 64, 0, stream>>>(kb, vb, St, Zc);
    attn_prefix<<<128, 1024, 0, stream>>>(St, Zc);
    attn_intra<<<4096, 64, 0, stream>>>(qb, kb, vb, St, Zc, h);
    ln_kernel<<<NROWS / 4, 256, 0, stream>>>(h, ln2g + l * 256, ln2b + l * 256, hn);
    gemm_bf16<<<dim3(256, 8, 1), 256, 0, stream>>>(
        hn, TU + l * 262144, nullptr, nullptr,
        bU + l * 1024, nullptr, nullptr,
        mid, nullptr, nullptr, nullptr, 1024, 256, 1);
    gemm_bf16<<<dim3(256, 2, 1), 256, 0, stream>>>(
        mid, TVd + l * 262144, nullptr, nullptr,
        bV + l * 256, nullptr, nullptr,
        nullptr, nullptr, nullptr, h, 256, 1024, 2);
  }
  out_proj<<<NROWS / 4, 256, 0, stream>>>(h, Wout, bout, out);
}

// Round 3
// 926.953 us; speedup vs baseline: 1.1171x; 1.0029x over previous
//
#include <hip/hip_runtime.h>
#include <math.h>

// ExpressionPerformer: B=16,G=2048,D=256,H=8,dh=32,FFN=1024,L=4
// Round-3 changes:
//  - gemm: software-pipelined K-loop: double-buffered LDS with global_load_lds
//    prefetch issued AFTER the (single) barrier -> load latency overlaps MFMA.
//    (round-2 had loads serial between two barriers; MfmaUtil was 10%)
//  - attention kernels: 4 chunks (4 waves) per 256-thread block (fewer dispatches)

#define GG 2048
#define DD 256
#define HD 32
#define NROWS 32768
#define NC 32
#define CS 64

typedef __attribute__((ext_vector_type(8))) short bf16x8;
typedef __attribute__((ext_vector_type(4))) float f32x4;

__device__ __forceinline__ short f2bf(float f) {
  union { float f; unsigned u; } v; v.f = f;
  unsigned r = v.u + 0x7FFFu + ((v.u >> 16) & 1u);
  return (short)(r >> 16);
}
__device__ __forceinline__ float bf2f(short s) {
  union { unsigned u; float f; } v; v.u = ((unsigned)(unsigned short)s) << 16;
  return v.f;
}
__device__ __forceinline__ void gld16(const short* g, short* l) {
  __builtin_amdgcn_global_load_lds(
      (const __attribute__((address_space(1))) void*)g,
      (__attribute__((address_space(3))) void*)l, 16, 0, 0);
}

// ---------------- embed: h = gene_emb + [sin(x*invf), cos(x*invf)] (masked) ----
__global__ __launch_bounds__(256) void embed_kernel(
    const float* __restrict__ x, const float* __restrict__ ge,
    const float* __restrict__ invf, float* __restrict__ h) {
  int bg = blockIdx.x * 4 + (threadIdx.x >> 6);
  int g = bg & (GG - 1);
  int lane = threadIdx.x & 63;
  float xv = x[bg];
  int d = lane * 4;
  float4 e;
  if (lane < 32) {
    float4 f = *(const float4*)&invf[d];
    e.x = sinf(xv * f.x); e.y = sinf(xv * f.y);
    e.z = sinf(xv * f.z); e.w = sinf(xv * f.w);
  } else {
    float4 f = *(const float4*)&invf[d - 128];
    e.x = cosf(xv * f.x); e.y = cosf(xv * f.y);
    e.z = cosf(xv * f.z); e.w = cosf(xv * f.w);
  }
  if (xv == -10.0f) { e.x = 0.f; e.y = 0.f; e.z = 0.f; e.w = 0.f; }
  float4 gv = *(const float4*)&ge[(size_t)g * DD + d];
  float4 o; o.x = gv.x + e.x; o.y = gv.y + e.y; o.z = gv.z + e.z; o.w = gv.w + e.w;
  *(float4*)&h[(size_t)bg * DD + d] = o;
}

// ---------------- layernorm (row of 256) -> bf16, 4 rows/block ----------------
__global__ __launch_bounds__(256) void ln_kernel(
    const float* __restrict__ h, const float* __restrict__ gamma,
    const float* __restrict__ beta, short* __restrict__ out) {
  int row = blockIdx.x * 4 + (threadIdx.x >> 6);
  int lane = threadIdx.x & 63;
  float4 xv = *(const float4*)&h[(size_t)row * DD + lane * 4];
  float s = xv.x + xv.y + xv.z + xv.w;
#pragma unroll
  for (int o = 1; o < 64; o <<= 1) s += __shfl_xor(s, o);
  float mean = s * (1.0f / 256.0f);
  float a = xv.x - mean, b = xv.y - mean, c = xv.z - mean, d = xv.w - mean;
  float s2 = a * a + b * b + c * c + d * d;
#pragma unroll
  for (int o = 1; o < 64; o <<= 1) s2 += __shfl_xor(s2, o);
  float rstd = rsqrtf(s2 * (1.0f / 256.0f) + 1e-5f);
  float4 g = *(const float4*)&gamma[lane * 4];
  float4 bb = *(const float4*)&beta[lane * 4];
  short4 o4;
  o4.x = f2bf(a * rstd * g.x + bb.x);
  o4.y = f2bf(b * rstd * g.y + bb.y);
  o4.z = f2bf(c * rstd * g.z + bb.z);
  o4.w = f2bf(d * rstd * g.w + bb.w);
  *(short4*)&out[(size_t)row * DD + lane * 4] = o4;
}

// ---------------- weight convert+transpose: W[K][N] -> WT[N][K] bf16 ----------
__global__ __launch_bounds__(256) void prep_weights(
    const float* __restrict__ Wq, const float* __restrict__ Wk,
    const float* __restrict__ Wv, const float* __restrict__ WU,
    const float* __restrict__ WV,
    short* __restrict__ TQ, short* __restrict__ TK, short* __restrict__ TV,
    short* __restrict__ TU, short* __restrict__ TVd) {
  int zz = blockIdx.z, l = blockIdx.y;
  const float* src; short* dst; int Kd, Nd;
  if (zz == 0) { src = Wq; dst = TQ; Kd = 256; Nd = 256; }
  else if (zz == 1) { src = Wk; dst = TK; Kd = 256; Nd = 256; }
  else if (zz == 2) { src = Wv; dst = TV; Kd = 256; Nd = 256; }
  else if (zz == 3) { src = WU; dst = TU; Kd = 256; Nd = 1024; }
  else { src = WV; dst = TVd; Kd = 1024; Nd = 256; }
  int tot = Kd * Nd;
  int e = blockIdx.x * 256 + threadIdx.x;
  if (e >= tot) return;
  int n = e / Kd, k = e - n * Kd;
  dst[(size_t)l * tot + e] = f2bf(src[(size_t)l * tot + (size_t)k * Nd + n]);
}

// ---------------- bf16 MFMA GEMM: C = A[M,K] * BT[N,K]^T + bias ---------------
// Double-buffered, prefetch-after-barrier pipeline. Swapped-operand MFMA:
// lane owns 4 consecutive n -> packed short4/float4 stores.
// epi 0: z<2 -> square, bf16 out (QKV);  1: gelu, bf16 out;  2: h += acc+bias
__global__ __launch_bounds__(256) void gemm_bf16(
    const short* __restrict__ A, const short* __restrict__ B0,
    const short* __restrict__ B1, const short* __restrict__ B2,
    const float* __restrict__ bias0, const float* __restrict__ bias1,
    const float* __restrict__ bias2,
    short* __restrict__ o0, short* __restrict__ o1, short* __restrict__ o2,
    float* __restrict__ outf, int N, int K, int epi) {
  __shared__ short As[2][4096];  // 128x32 bf16, 16B-chunk-major [kb][m]
  __shared__ short Bs[2][4096];
  int z = blockIdx.z;
  const short* Bt = (z == 0) ? B0 : (z == 1) ? B1 : B2;
  const float* bias = (z == 0) ? bias0 : (z == 1) ? bias1 : bias2;
  short* outz = (z == 0) ? o0 : (z == 1) ? o1 : o2;
  int m0 = blockIdx.x * 128, n0 = blockIdx.y * 128;
  int tid = threadIdx.x;
  int lane = tid & 63, w = tid >> 6;
  int q = lane >> 4, r = lane & 15;
  int wm = (w >> 1) * 64, wn = (w & 1) * 64;
  f32x4 vzero = {0.f, 0.f, 0.f, 0.f};
  f32x4 acc[4][4];
#pragma unroll
  for (int i = 0; i < 4; ++i)
#pragma unroll
    for (int j = 0; j < 4; ++j) acc[i][j] = vzero;

  int c0 = tid, c1 = tid + 256;
  const short* a0 = &A[(size_t)(m0 + (c0 & 127)) * K + (c0 >> 7) * 8];
  const short* a1 = &A[(size_t)(m0 + (c1 & 127)) * K + (c1 >> 7) * 8];
  const short* b0p = &Bt[(size_t)(n0 + (c0 & 127)) * K + (c0 >> 7) * 8];
  const short* b1p = &Bt[(size_t)(n0 + (c1 & 127)) * K + (c1 >> 7) * 8];

  // prologue: stage tile 0 into buffer 0
  gld16(a0, &As[0][c0 * 8]);
  gld16(a1, &As[0][c1 * 8]);
  gld16(b0p, &Bs[0][c0 * 8]);
  gld16(b1p, &Bs[0][c1 * 8]);

  int nIter = K >> 5;
  for (int it = 0; it < nIter; ++it) {
    int cur = it & 1;
    __builtin_amdgcn_s_waitcnt(0x0f70);  // vmcnt(0): my staged loads landed
    __syncthreads();                     // everyone's landed
    if (it + 1 < nIter) {                // prefetch next tile (overlaps MFMAs)
      int kn = (it + 1) << 5;
      int nxt = cur ^ 1;
      gld16(a0 + kn, &As[nxt][c0 * 8]);
      gld16(a1 + kn, &As[nxt][c1 * 8]);
      gld16(b0p + kn, &Bs[nxt][c0 * 8]);
      gld16(b1p + kn, &Bs[nxt][c1 * 8]);
    }
    bf16x8 af[4], bfr[4];
#pragma unroll
    for (int mt = 0; mt < 4; ++mt)
      af[mt] = *(const bf16x8*)&As[cur][(q * 128 + wm + mt * 16 + r) * 8];
#pragma unroll
    for (int nt = 0; nt < 4; ++nt)
      bfr[nt] = *(const bf16x8*)&Bs[cur][(q * 128 + wn + nt * 16 + r) * 8];
#pragma unroll
    for (int mt = 0; mt < 4; ++mt)
#pragma unroll
      for (int nt = 0; nt < 4; ++nt)
        acc[mt][nt] = __builtin_amdgcn_mfma_f32_16x16x32_bf16(bfr[nt], af[mt], acc[mt][nt], 0, 0, 0);
  }

  // epilogue: lane (q,r) in tile (mt,nt): m = wm+mt*16+r, n = wn+nt*16+q*4+[0..3]
  float4 bias4[4];
#pragma unroll
  for (int nt = 0; nt < 4; ++nt) bias4[nt] = *(const float4*)&bias[n0 + wn + nt * 16 + q * 4];
#pragma unroll
  for (int mt = 0; mt < 4; ++mt) {
    int m = m0 + wm + mt * 16 + r;
    size_t rowoff = (size_t)m * N + n0 + wn + q * 4;
#pragma unroll
    for (int nt = 0; nt < 4; ++nt) {
      f32x4 v = acc[mt][nt];
      v[0] += bias4[nt].x; v[1] += bias4[nt].y; v[2] += bias4[nt].z; v[3] += bias4[nt].w;
      if (epi == 0) {
        if (z < 2) { v[0] *= v[0]; v[1] *= v[1]; v[2] *= v[2]; v[3] *= v[3]; }
        short4 o; o.x = f2bf(v[0]); o.y = f2bf(v[1]); o.z = f2bf(v[2]); o.w = f2bf(v[3]);
        *(short4*)&outz[rowoff + nt * 16] = o;
      } else if (epi == 1) {
#pragma unroll
        for (int e = 0; e < 4; ++e) v[e] = 0.5f * v[e] * (1.0f + erff(v[e] * 0.70710678118654752f));
        short4 o; o.x = f2bf(v[0]); o.y = f2bf(v[1]); o.z = f2bf(v[2]); o.w = f2bf(v[3]);
        *(short4*)&outz[rowoff + nt * 16] = o;
      } else {
        float4 cur4 = *(float4*)&outf[rowoff + nt * 16];
        cur4.x += v[0]; cur4.y += v[1]; cur4.z += v[2]; cur4.w += v[3];
        *(float4*)&outf[rowoff + nt * 16] = cur4;
      }
    }
  }
}

// ---------------- attention A1: per (b,h,chunk) S_c = K^T V, z_c = sum k ------
// 4 chunks per block (one per wave)
__global__ __launch_bounds__(256) void attn_chunk_kv(
    const short* __restrict__ Kb, const short* __restrict__ Vb,
    float* __restrict__ St, float* __restrict__ Zc) {
  __shared__ short Kt[4][32 * 72];  // [f][t] padded
  __shared__ short Vt[4][32 * 72];  // [d][t]
  int wid = threadIdx.x >> 6;
  int blk = blockIdx.x * 4 + wid;
  int c = blk & (NC - 1), bh = blk >> 5;
  int b = bh >> 3, hh = bh & 7;
  int lane = threadIdx.x & 63, q = lane >> 4, r = lane & 15;
  size_t rowbase = ((size_t)(b * GG + c * CS + lane)) * DD + hh * HD;
#pragma unroll
  for (int j = 0; j < 4; ++j) {
    bf16x8 kv = *(const bf16x8*)&Kb[rowbase + j * 8];
    bf16x8 vv = *(const bf16x8*)&Vb[rowbase + j * 8];
#pragma unroll
    for (int e = 0; e < 8; ++e) {
      Kt[wid][(j * 8 + e) * 72 + lane] = kv[e];
      Vt[wid][(j * 8 + e) * 72 + lane] = vv[e];
    }
  }
  __syncthreads();
  f32x4 vzero = {0.f, 0.f, 0.f, 0.f};
  f32x4 acc[2][2];
#pragma unroll
  for (int i = 0; i < 2; ++i)
#pragma unroll
    for (int j = 0; j < 2; ++j) acc[i][j] = vzero;
#pragma unroll
  for (int ks = 0; ks < 2; ++ks) {
    bf16x8 afr[2], bfr[2];
#pragma unroll
    for (int mt = 0; mt < 2; ++mt) afr[mt] = *(const bf16x8*)&Kt[wid][(mt * 16 + r) * 72 + ks * 32 + q * 8];
#pragma unroll
    for (int nt = 0; nt < 2; ++nt) bfr[nt] = *(const bf16x8*)&Vt[wid][(nt * 16 + r) * 72 + ks * 32 + q * 8];
#pragma unroll
    for (int mt = 0; mt < 2; ++mt)
#pragma unroll
      for (int nt = 0; nt < 2; ++nt)
        acc[mt][nt] = __builtin_amdgcn_mfma_f32_16x16x32_bf16(afr[mt], bfr[nt], acc[mt][nt], 0, 0, 0);
  }
  float* stp = St + ((size_t)bh * NC + c) * 1024;
#pragma unroll
  for (int mt = 0; mt < 2; ++mt)
#pragma unroll
    for (int nt = 0; nt < 2; ++nt)
      *(f32x4*)&stp[(nt * 16 + r) * 32 + mt * 16 + q * 4] = acc[mt][nt];  // St[d][f]
  if (lane < 32) {
    float s = 0.f;
#pragma unroll
    for (int j = 0; j < 8; ++j) {
      bf16x8 kr = *(const bf16x8*)&Kt[wid][lane * 72 + j * 8];
#pragma unroll
      for (int e = 0; e < 8; ++e) s += bf2f(kr[e]);
    }
    Zc[((size_t)bh * NC + c) * 32 + lane] = s;
  }
}

// ---------------- attention A2: exclusive prefix over chunks ------------------
__global__ __launch_bounds__(1024) void attn_prefix(float* __restrict__ St, float* __restrict__ Zc) {
  int bh = blockIdx.x, i = threadIdx.x;
  float run = 0.f;
  float* p = St + (size_t)bh * NC * 1024 + i;
#pragma unroll
  for (int c = 0; c < NC; ++c) { float t = p[(size_t)c * 1024]; p[(size_t)c * 1024] = run; run += t; }
  if (i < 32) {
    float rz = 0.f;
    float* pz = Zc + (size_t)bh * NC * 32 + i;
#pragma unroll
    for (int c = 0; c < NC; ++c) { float t = pz[c * 32]; pz[c * 32] = rz; rz += t; }
  }
}

// ---------------- attention B: intra-chunk + apply, h += out ------------------
// 4 chunks per block (one per wave)
__global__ __launch_bounds__(256) void attn_intra(
    const short* __restrict__ Qb, const short* __restrict__ Kb,
    const short* __restrict__ Vb, const float* __restrict__ St,
    const float* __restrict__ Zc, float* __restrict__ h) {
  __shared__ short P[4][64 * 72];   // [t][s] bf16, padded
  __shared__ short Vt[4][32 * 72];  // [d][t]
  __shared__ float den[4][64];
  int wid = threadIdx.x >> 6;
  int blk = blockIdx.x * 4 + wid;
  int c = blk & (NC - 1), bh = blk >> 5;
  int b = bh >> 3, hh = bh & 7;
  int lane = threadIdx.x & 63, q = lane >> 4, r = lane & 15;
  size_t row0 = (size_t)b * GG + c * CS;

  const float* zp = Zc + ((size_t)bh * NC + c) * 32;
  float qz = 0.f;
  {
    size_t qoff = (row0 + lane) * DD + hh * HD;
#pragma unroll
    for (int j = 0; j < 4; ++j) {
      bf16x8 qv = *(const bf16x8*)&Qb[qoff + j * 8];
#pragma unroll
      for (int e = 0; e < 8; ++e) qz += bf2f(qv[e]) * zp[j * 8 + e];
    }
  }
  den[wid][lane] = qz;

  {
    size_t voff = (row0 + lane) * DD + hh * HD;
#pragma unroll
    for (int j = 0; j < 4; ++j) {
      bf16x8 vv = *(const bf16x8*)&Vb[voff + j * 8];
#pragma unroll
      for (int e = 0; e < 8; ++e) Vt[wid][(j * 8 + e) * 72 + lane] = vv[e];
    }
  }

  bf16x8 ak[4], bqf[4];
#pragma unroll
  for (int t4 = 0; t4 < 4; ++t4) {
    ak[t4]  = *(const bf16x8*)&Kb[(row0 + t4 * 16 + r) * DD + hh * HD + q * 8];
    bqf[t4] = *(const bf16x8*)&Qb[(row0 + t4 * 16 + r) * DD + hh * HD + q * 8];
  }
  f32x4 vzero = {0.f, 0.f, 0.f, 0.f};
  f32x4 pacc[4][4];
#pragma unroll
  for (int mt = 0; mt < 4; ++mt)
#pragma unroll
    for (int nt = 0; nt < 4; ++nt)
      pacc[mt][nt] = __builtin_amdgcn_mfma_f32_16x16x32_bf16(ak[mt], bqf[nt], vzero, 0, 0, 0);

  float rs[4] = {0.f, 0.f, 0.f, 0.f};
#pragma unroll
  for (int nt = 0; nt < 4; ++nt) {
    int t = nt * 16 + r;
#pragma unroll
    for (int mt = 0; mt < 4; ++mt) {
      short4 pk;
#pragma unroll
      for (int rr = 0; rr < 4; ++rr) {
        int s = mt * 16 + q * 4 + rr;
        float pv = (s <= t) ? pacc[mt][nt][rr] : 0.f;
        rs[nt] += pv;
        ((short*)&pk)[rr] = f2bf(pv);
      }
      *(short4*)&P[wid][t * 72 + mt * 16 + q * 4] = pk;
    }
  }
#pragma unroll
  for (int nt = 0; nt < 4; ++nt) {
    rs[nt] += __shfl_xor(rs[nt], 16);
    rs[nt] += __shfl_xor(rs[nt], 32);
  }
  __syncthreads();
  if (lane < 16) {
#pragma unroll
    for (int nt = 0; nt < 4; ++nt) den[wid][nt * 16 + lane] += rs[nt];
  }
  __syncthreads();

  f32x4 oacc[4][2];
#pragma unroll
  for (int mt = 0; mt < 4; ++mt)
#pragma unroll
    for (int nt2 = 0; nt2 < 2; ++nt2) oacc[mt][nt2] = vzero;
  const float* stp = St + ((size_t)bh * NC + c) * 1024;
#pragma unroll
  for (int nt2 = 0; nt2 < 2; ++nt2) {
    float4 s0 = *(const float4*)&stp[(nt2 * 16 + r) * 32 + q * 8];
    float4 s1 = *(const float4*)&stp[(nt2 * 16 + r) * 32 + q * 8 + 4];
    bf16x8 bs;
    bs[0] = f2bf(s0.x); bs[1] = f2bf(s0.y); bs[2] = f2bf(s0.z); bs[3] = f2bf(s0.w);
    bs[4] = f2bf(s1.x); bs[5] = f2bf(s1.y); bs[6] = f2bf(s1.z); bs[7] = f2bf(s1.w);
#pragma unroll
    for (int mt = 0; mt < 4; ++mt)
      oacc[mt][nt2] = __builtin_amdgcn_mfma_f32_16x16x32_bf16(bqf[mt], bs, oacc[mt][nt2], 0, 0, 0);
  }
#pragma unroll
  for (int ks = 0; ks < 2; ++ks) {
    bf16x8 ap[4];
#pragma unroll
    for (int mt = 0; mt < 4; ++mt)
      ap[mt] = *(const bf16x8*)&P[wid][(mt * 16 + r) * 72 + ks * 32 + q * 8];
#pragma unroll
    for (int nt2 = 0; nt2 < 2; ++nt2) {
      bf16x8 bv_ = *(const bf16x8*)&Vt[wid][(nt2 * 16 + r) * 72 + ks * 32 + q * 8];
#pragma unroll
      for (int mt = 0; mt < 4; ++mt)
        oacc[mt][nt2] = __builtin_amdgcn_mfma_f32_16x16x32_bf16(ap[mt], bv_, oacc[mt][nt2], 0, 0, 0);
    }
  }

#pragma unroll
  for (int mt = 0; mt < 4; ++mt) {
#pragma unroll
    for (int rr = 0; rr < 4; ++rr) {
      int t = mt * 16 + q * 4 + rr;
      float inv = 1.0f / (den[wid][t] + 1e-16f);
#pragma unroll
      for (int nt2 = 0; nt2 < 2; ++nt2) {
        int d = nt2 * 16 + r;
        size_t off = (row0 + t) * DD + hh * HD + d;
        h[off] += oacc[mt][nt2][rr] * inv;
      }
    }
  }
}

// ---------------- final projection: out = h @ Wout + bout ---------------------
__global__ __launch_bounds__(256) void out_proj(
    const float* __restrict__ h, const float* __restrict__ Wout,
    const float* __restrict__ bout, float* __restrict__ out) {
  int row = blockIdx.x * 4 + (threadIdx.x >> 6);
  int lane = threadIdx.x & 63;
  float4 a = *(const float4*)&h[(size_t)row * DD + lane * 4];
  float4 w = *(const float4*)&Wout[lane * 4];
  float s = a.x * w.x + a.y * w.y + a.z * w.z + a.w * w.w;
#pragma unroll
  for (int o = 1; o < 64; o <<= 1) s += __shfl_xor(s, o);
  if (lane == 0) out[row] = s + bout[0];
}

extern "C" void kernel_launch(void* const* d_in, const int* in_sizes, int n_in,
                              void* d_out, int out_size, void* d_ws, size_t ws_size,
                              hipStream_t stream) {
  const float* x    = (const float*)d_in[0];
  const float* ge   = (const float*)d_in[1];
  const float* invf = (const float*)d_in[2];
  const float* Wq   = (const float*)d_in[3];
  const float* bq   = (const float*)d_in[4];
  const float* Wk   = (const float*)d_in[5];
  const float* bk   = (const float*)d_in[6];
  const float* Wv   = (const float*)d_in[7];
  const float* bv   = (const float*)d_in[8];
  const float* ln1g = (const float*)d_in[9];
  const float* ln1b = (const float*)d_in[10];
  const float* ln2g = (const float*)d_in[11];
  const float* ln2b = (const float*)d_in[12];
  const float* WU   = (const float*)d_in[13];
  const float* bU   = (const float*)d_in[14];
  const float* WV   = (const float*)d_in[15];
  const float* bV   = (const float*)d_in[16];
  const float* Wout = (const float*)d_in[17];
  const float* bout = (const float*)d_in[18];
  float* out = (float*)d_out;

  char* ws = (char*)d_ws;
  float* h   = (float*)(ws + 0);            // 33.5 MB
  short* hn  = (short*)(ws + 33554432);     // 16.8 MB
  char*  R   = ws + 50331648;               // shared region
  short* qb  = (short*)(R + 0);
  short* kb  = (short*)(R + 16777216);
  short* vb  = (short*)(R + 33554432);
  float* St  = (float*)(R + 50331648);
  float* Zc  = (float*)(R + 67108864);
  short* mid = (short*)(R + 0);             // FFN phase (overlaps q/k/v in time)
  char*  WT  = R + 67633152;
  short* TQ  = (short*)(WT + 0);
  short* TK  = (short*)(WT + 524288);
  short* TVq = (short*)(WT + 1048576);
  short* TU  = (short*)(WT + 1572864);
  short* TVd = (short*)(WT + 3670016);

  prep_weights<<<dim3(1024, 4, 5), 256, 0, stream>>>(Wq, Wk, Wv, WU, WV, TQ, TK, TVq, TU, TVd);
  embed_kernel<<<NROWS / 4, 256, 0, stream>>>(x, ge, invf, h);

  for (int l = 0; l < 4; ++l) {
    ln_kernel<<<NROWS / 4, 256, 0, stream>>>(h, ln1g + l * 256, ln1b + l * 256, hn);
    gemm_bf16<<<dim3(256, 2, 3), 256, 0, stream>>>(
        hn, TQ + l * 65536, TK + l * 65536, TVq + l * 65536,
        bq + l * 256, bk + l * 256, bv + l * 256,
        qb, kb, vb, nullptr, 256, 256, 0);
    attn_chunk_kv<<<1024, 256, 0, stream>>>(kb, vb, St, Zc);
    attn_prefix<<<128, 1024, 0, stream>>>(St, Zc);
    attn_intra<<<1024, 256, 0, stream>>>(qb, kb, vb, St, Zc, h);
    ln_kernel<<<NROWS / 4, 256, 0, stream>>>(h, ln2g + l * 256, ln2b + l * 256, hn);
    gemm_bf16<<<dim3(256, 8, 1), 256, 0, stream>>>(
        hn, TU + l * 262144, nullptr, nullptr,
        bU + l * 1024, nullptr, nullptr,
        mid, nullptr, nullptr, nullptr, 1024, 256, 1);
    gemm_bf16<<<dim3(256, 2, 1), 256, 0, stream>>>(
        mid, TVd + l * 262144, nullptr, nullptr,
        bV + l * 256, nullptr, nullptr,
        nullptr, nullptr, nullptr, h, 256, 1024, 2);
  }
  out_proj<<<NROWS / 4, 256, 0, stream>>>(h, Wout, bout, out);
}